// Round 2
// baseline (28619.278 us; speedup 1.0000x reference)
//
#include <hip/hip_runtime.h>
#include <cstdint>
#include <cstddef>

using u16 = unsigned short;
typedef short short8 __attribute__((ext_vector_type(8)));
typedef float f32x4 __attribute__((ext_vector_type(4)));

#define LN_EPS 1e-5f
#define ATT_BETA 0.125f

__device__ __forceinline__ u16 f2bf(float f){
  uint32_t u = __float_as_uint(f);
  u += 0x7fffu + ((u >> 16) & 1u);
  return (u16)(u >> 16);
}
__device__ __forceinline__ float bf2f(u16 h){
  return __uint_as_float(((uint32_t)h) << 16);
}
__device__ __forceinline__ float wred_sum(float v){
  #pragma unroll
  for(int o=32;o;o>>=1) v += __shfl_xor(v,o,64);
  return v;
}
__device__ __forceinline__ float wred_max(float v){
  #pragma unroll
  for(int o=32;o;o>>=1) v = fmaxf(v, __shfl_xor(v,o,64));
  return v;
}
__device__ __forceinline__ void async16(const void* g, void* l){
  __builtin_amdgcn_global_load_lds((const __attribute__((address_space(1))) void*)g,
                                   (__attribute__((address_space(3))) void*)l, 16, 0, 0);
}

// ---------------- generic bf16 MFMA GEMM: C[M,N] = A[M,K] * B[N,K]^T (B row stride ldb) -------
// EPI: 0=bf16 out, 1=bf16+relu out, 2=t += alpha*acc (alpha=softplus(araw[blk])),
//      3=encode epilogue (write t rows b*197+1+n, add b_enc + pos), 4=decode (skip CLS, +b_dec)
template<int EPI>
__global__ __launch_bounds__(256)
void gemm_bt(const u16* __restrict__ A, const u16* __restrict__ B,
             u16* __restrict__ Cb, float* __restrict__ Cf,
             int M, int N, int K, int ldb,
             const float* __restrict__ aux0, const float* __restrict__ aux1,
             const float* __restrict__ araw, int blk)
{
  __shared__ u16 lA[128*32];
  __shared__ u16 lB[128*32];
  int tid = threadIdx.x;
  int w = tid >> 6, l = tid & 63;
  int wm = w >> 1, wn = w & 1;
  int m0 = blockIdx.y * 128, n0 = blockIdx.x * 128;
  int lr = l >> 2;           // row within 16-row chunk
  int lc = (l & 3) * 8;      // col (elements) within 32-wide K slab
  f32x4 acc[4][4];
  #pragma unroll
  for(int i=0;i<4;i++)
    #pragma unroll
    for(int j=0;j<4;j++) acc[i][j] = (f32x4){0.f,0.f,0.f,0.f};
  int fm = l & 15, fq = (l >> 4) * 8;

  for(int kt=0; kt<K; kt+=32){
    __syncthreads();
    #pragma unroll
    for(int c=0;c<2;c++){
      int rr = (w*2+c)*16;
      int ga = m0 + rr + lr; if(ga > M-1) ga = M-1;
      async16(A + (size_t)ga*K + kt + lc, &lA[rr*32]);
      int gb = n0 + rr + lr; if(gb > N-1) gb = N-1;
      async16(B + (size_t)gb*ldb + kt + lc, &lB[rr*32]);
    }
    __syncthreads();
    short8 af[4], bfv[4];
    #pragma unroll
    for(int i=0;i<4;i++) af[i]  = *(const short8*)&lA[(wm*64 + i*16 + fm)*32 + fq];
    #pragma unroll
    for(int j=0;j<4;j++) bfv[j] = *(const short8*)&lB[(wn*64 + j*16 + fm)*32 + fq];
    #pragma unroll
    for(int i=0;i<4;i++)
      #pragma unroll
      for(int j=0;j<4;j++)
        acc[i][j] = __builtin_amdgcn_mfma_f32_16x16x32_bf16(af[i], bfv[j], acc[i][j], 0, 0, 0);
  }

  float alpha = 0.f;
  if(EPI==2) alpha = log1pf(__expf(araw[blk]));

  #pragma unroll
  for(int i=0;i<4;i++){
    int row_b = m0 + wm*64 + i*16 + (l>>4)*4;
    #pragma unroll
    for(int j=0;j<4;j++){
      int col = n0 + wn*64 + j*16 + (l&15);
      #pragma unroll
      for(int r=0;r<4;r++){
        int row = row_b + r;
        if(row >= M) continue;
        float v = acc[i][j][r];
        if(EPI==0){
          Cb[(size_t)row*N + col] = f2bf(v);
        } else if(EPI==1){
          Cb[(size_t)row*N + col] = f2bf(v > 0.f ? v : 0.f);
        } else if(EPI==2){
          Cf[(size_t)row*N + col] += alpha * v;
        } else if(EPI==3){
          int pb = row / 196, pn = row - pb*196;
          Cf[((size_t)pb*197 + 1 + pn)*768 + col] = v + aux0[col] + aux1[(size_t)(1+pn)*768 + col];
        } else {
          int pb = row / 197, rr2 = row - pb*197;
          if(rr2 > 0) Cf[((size_t)pb*196 + rr2 - 1)*768 + col] = v + aux0[col];
        }
      }
    }
  }
}

// ---------------- LN: mode 0 = EnergyLN (scalar gamma + per-dim bias), 1 = final LN ----------
__global__ __launch_bounds__(256)
void norm_k(const float* __restrict__ t, u16* __restrict__ out,
            const float* __restrict__ gv, const float* __restrict__ bv, int blk, int mode)
{
  __shared__ float r1[4], r2[4];
  int row = blockIdx.x;
  const float* tr = t + (size_t)row*768;
  int tid = threadIdx.x, w = tid>>6, l = tid&63;
  float s=0.f, s2=0.f;
  for(int i=tid;i<768;i+=256){ float v = tr[i]; s += v; s2 += v*v; }
  s = wred_sum(s); s2 = wred_sum(s2);
  if(l==0){ r1[w]=s; r2[w]=s2; }
  __syncthreads();
  s  = r1[0]+r1[1]+r1[2]+r1[3];
  s2 = r2[0]+r2[1]+r2[2]+r2[3];
  float mu  = s * (1.0f/768.0f);
  float var = s2 * (1.0f/768.0f) - mu*mu;
  float rs  = rsqrtf(var + LN_EPS);
  u16* orow = out + (size_t)row*768;
  if(mode==0){
    float gm = gv[blk];
    const float* bb = bv + blk*768;
    for(int i=tid;i<768;i+=256) orow[i] = f2bf((tr[i]-mu)*rs*gm + bb[i]);
  } else {
    for(int i=tid;i<768;i+=256) orow[i] = f2bf((tr[i]-mu)*rs*gv[i] + bv[i]);
  }
}

// ---------------- fused attention per (b,h): A=softmax(beta QK^T); Gq=A K -> Qb; Gk=A^T Q -> Kb
__global__ __launch_bounds__(256)
void attn_fused_k(u16* __restrict__ Qb, u16* __restrict__ Kb){
  __shared__ u16  Kzj[64*198];    // Kzj[z*198+j] = K[j][z]            25,344 B
  __shared__ float Qzr[64*17];    // Qzr[z*17+r]  = Q[q0+r][z]          4,352 B
  __shared__ float At3[197*17];   // At3[j*17+r]  = A[q0+r][j]         13,396 B
  int bh = blockIdx.x, b = bh/12, h = bh - b*12;
  u16* Qg = Qb + (size_t)b*197*768 + h*64;
  u16* Kg = Kb + (size_t)b*197*768 + h*64;
  int tid = threadIdx.x, w = tid>>6, l = tid&63;
  for(int idx=tid; idx<197*64; idx+=256){
    int j = idx>>6, z = idx&63;
    Kzj[z*198 + j] = Kg[(size_t)j*768 + z];
  }
  float gkacc[50];
  #pragma unroll
  for(int k=0;k<50;k++) gkacc[k]=0.f;
  int j0=l, j1=l+64, j2=l+128, j3=l+192;
  bool v3 = (j3 < 197);
  int j3c = v3 ? j3 : 196;

  for(int q0=0;q0<197;q0+=16){
    __syncthreads();  // protects Qzr & At3 rewrite vs previous-tile readers
    for(int idx=tid; idx<1024; idx+=256){
      int r = idx>>6, z = idx&63;
      int q = q0 + r;
      Qzr[z*17 + r] = (q<197) ? bf2f(Qg[(size_t)q*768 + z]) : 0.f;
    }
    __syncthreads();
    // ---- scores: wave w -> q rows w*4..w*4+3; lane -> j ∈ {l, l+64, l+128, l+192}
    float s[4][4];
    #pragma unroll
    for(int a=0;a<4;a++)
      #pragma unroll
      for(int c=0;c<4;c++) s[a][c]=0.f;
    for(int z=0;z<64;z++){
      const u16* kr = &Kzj[z*198];
      float k0v=bf2f(kr[j0]), k1v=bf2f(kr[j1]), k2v=bf2f(kr[j2]), k3v=bf2f(kr[j3c]);
      const float* qp = &Qzr[z*17 + (w<<2)];
      float qa=qp[0], qbv=qp[1], qc=qp[2], qd=qp[3];
      s[0][0]+=qa*k0v;  s[0][1]+=qa*k1v;  s[0][2]+=qa*k2v;  s[0][3]+=qa*k3v;
      s[1][0]+=qbv*k0v; s[1][1]+=qbv*k1v; s[1][2]+=qbv*k2v; s[1][3]+=qbv*k3v;
      s[2][0]+=qc*k0v;  s[2][1]+=qc*k1v;  s[2][2]+=qc*k2v;  s[2][3]+=qc*k3v;
      s[3][0]+=qd*k0v;  s[3][1]+=qd*k1v;  s[3][2]+=qd*k2v;  s[3][3]+=qd*k3v;
    }
    #pragma unroll
    for(int qq=0;qq<4;qq++){
      int r = (w<<2)+qq, q = q0 + r;
      if(q > 196) continue;                  // wave-uniform
      float sv3 = v3 ? s[qq][3] : -3e38f;
      float m = fmaxf(fmaxf(s[qq][0],s[qq][1]), fmaxf(s[qq][2],sv3));
      m = wred_max(m);
      float e0 = __expf(ATT_BETA*(s[qq][0]-m));
      float e1 = __expf(ATT_BETA*(s[qq][1]-m));
      float e2 = __expf(ATT_BETA*(s[qq][2]-m));
      float e3 = v3 ? __expf(ATT_BETA*(s[qq][3]-m)) : 0.f;
      float inv = 1.f / wred_sum(e0+e1+e2+e3);
      At3[j0*17 + r] = e0*inv;
      At3[j1*17 + r] = e1*inv;
      At3[j2*17 + r] = e2*inv;
      if(v3) At3[j3*17 + r] = e3*inv;
    }
    __syncthreads();
    // ---- Gq: thread (w,l): z=l, rows r=w*4..w*4+3
    float qreg[16];
    #pragma unroll
    for(int r=0;r<16;r++) qreg[r] = Qzr[l*17 + r];
    float gq0=0.f, gq1=0.f, gq2=0.f, gq3=0.f;
    const u16* krow = &Kzj[l*198];
    for(int j=0;j<197;j++){
      float kv = bf2f(krow[j]);
      const float* ap = &At3[j*17 + (w<<2)];
      gq0 += ap[0]*kv; gq1 += ap[1]*kv; gq2 += ap[2]*kv; gq3 += ap[3]*kv;
    }
    {
      int qb = q0 + (w<<2);
      if(qb+0 < 197) Qg[(size_t)(qb+0)*768 + l] = f2bf(gq0);
      if(qb+1 < 197) Qg[(size_t)(qb+1)*768 + l] = f2bf(gq1);
      if(qb+2 < 197) Qg[(size_t)(qb+2)*768 + l] = f2bf(gq2);
      if(qb+3 < 197) Qg[(size_t)(qb+3)*768 + l] = f2bf(gq3);
    }
    // ---- Gk accumulate: thread (w,l): z=l, own j = 4k+w  (stale At3 rows × qreg=0 are safe)
    for(int k2=0;k2<50;k2++){
      int j = 4*k2 + w;
      if(j >= 197) continue;
      const float* ap = &At3[j*17];
      #pragma unroll
      for(int r=0;r<16;r++) gkacc[k2] += ap[r]*qreg[r];
    }
  }
  for(int k2=0;k2<50;k2++){
    int j = 4*k2 + w;
    if(j < 197) Kg[(size_t)j*768 + l] = f2bf(gkacc[k2]);
  }
}

// ---------------- small utility kernels ----------------
__global__ void cvt_k(const float* __restrict__ in, u16* __restrict__ out, int n){
  for(int i=blockIdx.x*256+threadIdx.x; i<n; i+=gridDim.x*256) out[i] = f2bf(in[i]);
}

// dst[c*dstride + coff + r] = bf16(src[r*C + c]); R,C multiples of 32
__global__ __launch_bounds__(256)
void tr_k(const float* __restrict__ src, u16* __restrict__ dst, int R, int C, int dstride, int coff){
  __shared__ float tile[32][33];
  int c0 = blockIdx.x*32, r0 = blockIdx.y*32;
  int tx = threadIdx.x & 31, ty = threadIdx.x >> 5;
  for(int i=ty;i<32;i+=8) tile[i][tx] = src[(size_t)(r0+i)*C + c0 + tx];
  __syncthreads();
  for(int i=ty;i<32;i+=8) dst[(size_t)(c0+i)*dstride + coff + r0 + tx] = f2bf(tile[tx][i]);
}

__global__ void fill_cls_k(float* __restrict__ t, const float* __restrict__ cls, const float* __restrict__ pos){
  int b = blockIdx.x;
  for(int i=threadIdx.x;i<768;i+=256) t[(size_t)b*197*768 + i] = cls[i] + pos[i];
}

// ---------------- launch ----------------
extern "C" void kernel_launch(void* const* d_in, const int* in_sizes, int n_in,
                              void* d_out, int out_size, void* d_ws, size_t ws_size,
                              hipStream_t stream){
  const float* x      = (const float*)d_in[0];
  const float* W_enc  = (const float*)d_in[1];
  const float* b_enc  = (const float*)d_in[2];
  const float* cls    = (const float*)d_in[3];
  const float* pos    = (const float*)d_in[4];
  const float* gamma  = (const float*)d_in[5];
  const float* bias   = (const float*)d_in[6];
  const float* Wq     = (const float*)d_in[7];
  const float* Wk     = (const float*)d_in[8];
  const float* Whn    = (const float*)d_in[9];
  const float* araw   = (const float*)d_in[10];
  const float* ln_g   = (const float*)d_in[11];
  const float* ln_b   = (const float*)d_in[12];
  const float* W_dec  = (const float*)d_in[13];
  const float* b_dec  = (const float*)d_in[14];
  float* out = (float*)d_out;
  (void)in_sizes; (void)n_in; (void)out_size;

  const int M  = 64*197;   // 12608
  const int MX = 64*196;   // 12544

  // ---- workspace: 96,829,440 bytes total ----
  char* p = (char*)d_ws;
  float* t  = (float*)p;             p += (size_t)M*768*4;   // 38,731,776
  u16*   g  = (u16*)p;               p += (size_t)M*768*2;   // 19,365,888
  u16*   Qb = (u16*)p;               p += (size_t)M*768*2;   // 19,365,888 (Q -> Gq -> hop chunk; xb at encode)
  u16*   Kb = (u16*)p;               p += (size_t)M*768*2;   // 19,365,888 (K -> Gk; WencT/WdecT overlays)
  if((size_t)(p - (char*)d_ws) > ws_size) return;

  // ---- weights live inside d_out (28.3 MB of 38.5 MB; dead before decode overwrites) ----
  u16* Wall = (u16*)d_out;
  u16* Wqb  = Wall;              // 2 x 589824   (Wq rows [hz][d])
  u16* Wkb  = Wall + 1179648;    // 2 x 589824
  u16* WqT  = Wall + 2359296;    // 2 x 589824   (WqT[d][hz])
  u16* WkT  = Wall + 3538944;    // 2 x 589824
  u16* WhnT = Wall + 4718592;    // 2 x 2359296  (WhnT[n][k])
  u16* WhnB = Wall + 9437184;    // 2 x 2359296  (Whn bf16, row-major [d][n], ldb=3072)
  u16* xb    = Qb;               // encode-time overlay
  u16* WencT = Kb;               // encode-time overlay (1.18MB)
  u16* WdecT = Kb;               // decode-time overlay

  // ---- weight prep (every call; d_ws/d_out are re-poisoned each launch) ----
  for(int b=0;b<2;b++){
    cvt_k<<<512,256,0,stream>>>(Wq + (size_t)b*589824, Wqb + (size_t)b*589824, 589824);
    cvt_k<<<512,256,0,stream>>>(Wk + (size_t)b*589824, Wkb + (size_t)b*589824, 589824);
    tr_k<<<dim3(24,24),256,0,stream>>>(Wq + (size_t)b*589824, WqT + (size_t)b*589824, 768,768, 768, 0);
    tr_k<<<dim3(24,24),256,0,stream>>>(Wk + (size_t)b*589824, WkT + (size_t)b*589824, 768,768, 768, 0);
    tr_k<<<dim3(96,24),256,0,stream>>>(Whn + (size_t)b*2359296, WhnT + (size_t)b*2359296, 768,3072, 768, 0);
    cvt_k<<<2048,256,0,stream>>>(Whn + (size_t)b*2359296, WhnB + (size_t)b*2359296, 2359296);
  }

  // ---- encode: t = [cls; x@W_enc + b_enc] + pos ----
  cvt_k<<<1024,256,0,stream>>>(x, xb, MX*768);
  tr_k<<<dim3(24,24),256,0,stream>>>(W_enc, WencT, 768,768, 768, 0);
  fill_cls_k<<<64,256,0,stream>>>(t, cls, pos);
  gemm_bt<3><<<dim3(6,98),256,0,stream>>>(xb, WencT, nullptr, t, MX, 768, 768, 768, b_enc, pos, nullptr, 0);

  // ---- energy-descent blocks ----
  for(int blk=0; blk<2; blk++){
    for(int s=0; s<4; s++){
      norm_k<<<M,256,0,stream>>>(t, g, gamma, bias, blk, 0);
      gemm_bt<0><<<dim3(6,99),256,0,stream>>>(g, Wqb + (size_t)blk*589824, Qb, nullptr,
                                              M, 768, 768, 768, nullptr, nullptr, nullptr, 0);
      gemm_bt<0><<<dim3(6,99),256,0,stream>>>(g, Wkb + (size_t)blk*589824, Kb, nullptr,
                                              M, 768, 768, 768, nullptr, nullptr, nullptr, 0);
      attn_fused_k<<<768,256,0,stream>>>(Qb, Kb);          // Qb := Gq, Kb := Gk (in place)
      gemm_bt<2><<<dim3(6,99),256,0,stream>>>(Qb, WqT + (size_t)blk*589824, nullptr, t,
                                              M, 768, 768, 768, nullptr, nullptr, araw, blk);
      gemm_bt<2><<<dim3(6,99),256,0,stream>>>(Kb, WkT + (size_t)blk*589824, nullptr, t,
                                              M, 768, 768, 768, nullptr, nullptr, araw, blk);
      for(int c=0;c<4;c++){   // Hopfield in 4 N=768 chunks through Qb
        gemm_bt<1><<<dim3(6,99),256,0,stream>>>(g, WhnT + (size_t)blk*2359296 + (size_t)c*589824,
                                                Qb, nullptr, M, 768, 768, 768, nullptr, nullptr, nullptr, 0);
        gemm_bt<2><<<dim3(6,99),256,0,stream>>>(Qb, WhnB + (size_t)blk*2359296 + (size_t)c*768,
                                                nullptr, t, M, 768, 768, 3072, nullptr, nullptr, araw, blk);
      }
    }
  }

  // ---- decode: LN -> GEMM -> drop CLS ----
  tr_k<<<dim3(24,24),256,0,stream>>>(W_dec, WdecT, 768,768, 768, 0);
  norm_k<<<M,256,0,stream>>>(t, g, ln_g, ln_b, 0, 1);
  gemm_bt<4><<<dim3(6,99),256,0,stream>>>(g, WdecT, nullptr, out, M, 768, 768, 768, b_dec, nullptr, nullptr, 0);
}

// Round 4
// 7886.768 us; speedup vs baseline: 3.6288x; 3.6288x over previous
//
#include <hip/hip_runtime.h>
#include <cstdint>
#include <cstddef>

using u16 = unsigned short;
typedef short short8 __attribute__((ext_vector_type(8)));
typedef float f32x4 __attribute__((ext_vector_type(4)));

#define LN_EPS 1e-5f
#define ATT_BETA 0.125f

__device__ __forceinline__ u16 f2bf(float f){
  uint32_t u = __float_as_uint(f);
  u += 0x7fffu + ((u >> 16) & 1u);
  return (u16)(u >> 16);
}
__device__ __forceinline__ float bf2f(u16 h){
  return __uint_as_float(((uint32_t)h) << 16);
}
__device__ __forceinline__ float wred_sum(float v){
  #pragma unroll
  for(int o=32;o;o>>=1) v += __shfl_xor(v,o,64);
  return v;
}
__device__ __forceinline__ void async16(const void* g, void* l){
  __builtin_amdgcn_global_load_lds((const __attribute__((address_space(1))) void*)g,
                                   (__attribute__((address_space(3))) void*)l, 16, 0, 0);
}

// ---------------- generic bf16 MFMA GEMM: C[M,N] = A[M,K] * B[N,K]^T (B row stride ldb) -------
// EPI: 1=bf16+relu out (stride 768), 2=t += alpha*acc, 3=encode epilogue, 4=decode epilogue,
//      5=dual store: col<768 -> Cb, col>=768 -> Cb2 (both stride 768)
// ASPL: A operand split: k<768 from A, k>=768 from A2 (both row stride 768)
template<int EPI, int ASPL>
__global__ __launch_bounds__(256)
void gemm_bt(const u16* __restrict__ A, const u16* __restrict__ A2,
             const u16* __restrict__ B,
             u16* __restrict__ Cb, u16* __restrict__ Cb2, float* __restrict__ Cf,
             int M, int N, int K, int ldb,
             const float* __restrict__ aux0, const float* __restrict__ aux1,
             const float* __restrict__ araw, int blk)
{
  __shared__ u16 lA[128*32];
  __shared__ u16 lB[128*32];
  int tid = threadIdx.x;
  int w = tid >> 6, l = tid & 63;
  int wm = w >> 1, wn = w & 1;
  int m0 = blockIdx.y * 128, n0 = blockIdx.x * 128;
  int lr = l >> 2;           // row within 16-row chunk
  int lc = (l & 3) * 8;      // col (elements) within 32-wide K slab
  f32x4 acc[4][4];
  #pragma unroll
  for(int i=0;i<4;i++)
    #pragma unroll
    for(int j=0;j<4;j++) acc[i][j] = (f32x4){0.f,0.f,0.f,0.f};
  int fm = l & 15, fq = (l >> 4) * 8;

  for(int kt=0; kt<K; kt+=32){
    __syncthreads();
    const u16* Asrc = A; int kcol = kt;
    if(ASPL){ if(kt >= 768){ Asrc = A2; kcol = kt - 768; } }
    int lda = ASPL ? 768 : K;
    #pragma unroll
    for(int c=0;c<2;c++){
      int rr = (w*2+c)*16;
      int ga = m0 + rr + lr; if(ga > M-1) ga = M-1;
      async16(Asrc + (size_t)ga*lda + kcol + lc, &lA[rr*32]);
      int gb = n0 + rr + lr; if(gb > N-1) gb = N-1;
      async16(B + (size_t)gb*ldb + kt + lc, &lB[rr*32]);
    }
    __syncthreads();
    short8 af[4], bfv[4];
    #pragma unroll
    for(int i=0;i<4;i++) af[i]  = *(const short8*)&lA[(wm*64 + i*16 + fm)*32 + fq];
    #pragma unroll
    for(int j=0;j<4;j++) bfv[j] = *(const short8*)&lB[(wn*64 + j*16 + fm)*32 + fq];
    #pragma unroll
    for(int i=0;i<4;i++)
      #pragma unroll
      for(int j=0;j<4;j++)
        acc[i][j] = __builtin_amdgcn_mfma_f32_16x16x32_bf16(af[i], bfv[j], acc[i][j], 0, 0, 0);
  }

  float alpha = 0.f;
  if(EPI==2) alpha = log1pf(__expf(araw[blk]));

  #pragma unroll
  for(int i=0;i<4;i++){
    int row_b = m0 + wm*64 + i*16 + (l>>4)*4;
    #pragma unroll
    for(int j=0;j<4;j++){
      int col = n0 + wn*64 + j*16 + (l&15);
      #pragma unroll
      for(int r=0;r<4;r++){
        int row = row_b + r;
        if(row >= M) continue;
        float v = acc[i][j][r];
        if(EPI==1){
          Cb[(size_t)row*768 + col] = f2bf(v > 0.f ? v : 0.f);
        } else if(EPI==2){
          Cf[(size_t)row*768 + col] += alpha * v;
        } else if(EPI==3){
          int pb = row / 196, pn = row - pb*196;
          Cf[((size_t)pb*197 + 1 + pn)*768 + col] = v + aux0[col] + aux1[(size_t)(1+pn)*768 + col];
        } else if(EPI==4){
          int pb = row / 197, rr2 = row - pb*197;
          if(rr2 > 0) Cf[((size_t)pb*196 + rr2 - 1)*768 + col] = v + aux0[col];
        } else { // EPI==5
          if(col < 768) Cb[(size_t)row*768 + col] = f2bf(v);
          else          Cb2[(size_t)row*768 + col - 768] = f2bf(v);
        }
      }
    }
  }
}

// ---------------- LN: mode 0 = EnergyLN (scalar gamma + per-dim bias), 1 = final LN ----------
__global__ __launch_bounds__(256)
void norm_k(const float* __restrict__ t, u16* __restrict__ out,
            const float* __restrict__ gv, const float* __restrict__ bv, int blk, int mode)
{
  __shared__ float r1[4], r2[4];
  int row = blockIdx.x;
  const float* tr = t + (size_t)row*768;
  int tid = threadIdx.x, w = tid>>6, l = tid&63;
  float s=0.f, s2=0.f;
  for(int i=tid;i<768;i+=256){ float v = tr[i]; s += v; s2 += v*v; }
  s = wred_sum(s); s2 = wred_sum(s2);
  if(l==0){ r1[w]=s; r2[w]=s2; }
  __syncthreads();
  s  = r1[0]+r1[1]+r1[2]+r1[3];
  s2 = r2[0]+r2[1]+r2[2]+r2[3];
  float mu  = s * (1.0f/768.0f);
  float var = s2 * (1.0f/768.0f) - mu*mu;
  float rs  = rsqrtf(var + LN_EPS);
  u16* orow = out + (size_t)row*768;
  if(mode==0){
    float gm = gv[blk];
    const float* bb = bv + blk*768;
    for(int i=tid;i<768;i+=256) orow[i] = f2bf((tr[i]-mu)*rs*gm + bb[i]);
  } else {
    for(int i=tid;i<768;i+=256) orow[i] = f2bf((tr[i]-mu)*rs*gv[i] + bv[i]);
  }
}

// ---------------- attention scores: A = softmax rows, + stats (M, 1/L). Grid: chunk*4 --------
// A row stride 224; cols 197..223 zeroed; rows >=197 left untouched.
__global__ __launch_bounds__(256)
void scores_k(const u16* __restrict__ Qb, const u16* __restrict__ Kb,
              u16* __restrict__ A, float* __restrict__ Mst, float* __restrict__ Lst, int bh0)
{
  int bhl = blockIdx.x >> 2, stripe = blockIdx.x & 3;
  int bh = bh0 + bhl, b = bh/12, h = bh - b*12;
  const u16* Qg = Qb + (size_t)b*197*768 + h*64;
  const u16* Kg = Kb + (size_t)b*197*768 + h*64;
  int tid = threadIdx.x, w = tid>>6, l = tid&63;
  int q0 = stripe*64 + w*16;
  int qa = q0 + (l&15); if(qa > 196) qa = 196;
  int zq = (l>>4)*8;
  short8 aof0 = *(const short8*)(Qg + (size_t)qa*768 + zq);
  short8 aof1 = *(const short8*)(Qg + (size_t)qa*768 + 32 + zq);
  f32x4 acc[13];
  #pragma unroll
  for(int nt=0;nt<13;nt++) acc[nt] = (f32x4){0.f,0.f,0.f,0.f};
  #pragma unroll
  for(int nt=0;nt<13;nt++){
    int jb = nt*16 + (l&15); if(jb > 196) jb = 196;
    short8 b0 = *(const short8*)(Kg + (size_t)jb*768 + zq);
    short8 b1 = *(const short8*)(Kg + (size_t)jb*768 + 32 + zq);
    acc[nt] = __builtin_amdgcn_mfma_f32_16x16x32_bf16(aof0, b0, acc[nt], 0,0,0);
    acc[nt] = __builtin_amdgcn_mfma_f32_16x16x32_bf16(aof1, b1, acc[nt], 0,0,0);
  }
  // mask invalid cols
  #pragma unroll
  for(int nt=0;nt<13;nt++){
    if((l&15) + 16*nt > 196){
      acc[nt][0]=-3e38f; acc[nt][1]=-3e38f; acc[nt][2]=-3e38f; acc[nt][3]=-3e38f;
    }
  }
  float mx[4] = {-3e38f,-3e38f,-3e38f,-3e38f};
  #pragma unroll
  for(int nt=0;nt<13;nt++)
    #pragma unroll
    for(int r=0;r<4;r++) mx[r] = fmaxf(mx[r], acc[nt][r]);
  #pragma unroll
  for(int o=1;o<16;o<<=1)
    #pragma unroll
    for(int r=0;r<4;r++) mx[r] = fmaxf(mx[r], __shfl_xor(mx[r], o, 64));
  float ls[4] = {0.f,0.f,0.f,0.f};
  #pragma unroll
  for(int nt=0;nt<13;nt++)
    #pragma unroll
    for(int r=0;r<4;r++){
      float e = __expf(ATT_BETA*(acc[nt][r]-mx[r]));
      acc[nt][r] = e; ls[r] += e;
    }
  #pragma unroll
  for(int o=1;o<16;o<<=1)
    #pragma unroll
    for(int r=0;r<4;r++) ls[r] += __shfl_xor(ls[r], o, 64);
  float inv[4];
  #pragma unroll
  for(int r=0;r<4;r++) inv[r] = 1.f/ls[r];

  #pragma unroll
  for(int r=0;r<4;r++){
    int row = q0 + (l>>4)*4 + r;
    if(row > 196) continue;
    size_t base = ((size_t)bhl*208 + row)*224;
    #pragma unroll
    for(int nt=0;nt<13;nt++) A[base + (l&15) + 16*nt] = f2bf(acc[nt][r]*inv[r]);
    A[base + 208 + (l&15)] = 0;
  }
  if((l&15)==0){
    #pragma unroll
    for(int r=0;r<4;r++){
      int row = q0 + (l>>4)*4 + r;
      if(row < 208){
        Mst[(size_t)bhl*208 + row] = (row<197)? mx[r] : 0.f;
        Lst[(size_t)bhl*208 + row] = (row<197)? inv[r] : 0.f;
      }
    }
  }
}

// ---------------- attention scores transposed: At[j][q] via S^T = K Q^T + saved stats --------
__global__ __launch_bounds__(256)
void scoresT_k(const u16* __restrict__ Qb, const u16* __restrict__ Kb,
               u16* __restrict__ At, const float* __restrict__ Mst, const float* __restrict__ Lst,
               int bh0)
{
  int bhl = blockIdx.x >> 2, stripe = blockIdx.x & 3;
  int bh = bh0 + bhl, b = bh/12, h = bh - b*12;
  const u16* Qg = Qb + (size_t)b*197*768 + h*64;
  const u16* Kg = Kb + (size_t)b*197*768 + h*64;
  int tid = threadIdx.x, w = tid>>6, l = tid&63;
  int j0 = stripe*64 + w*16;
  int ja = j0 + (l&15); if(ja > 196) ja = 196;
  int zq = (l>>4)*8;
  short8 aof0 = *(const short8*)(Kg + (size_t)ja*768 + zq);
  short8 aof1 = *(const short8*)(Kg + (size_t)ja*768 + 32 + zq);
  f32x4 acc[13];
  #pragma unroll
  for(int nt=0;nt<13;nt++) acc[nt] = (f32x4){0.f,0.f,0.f,0.f};
  #pragma unroll
  for(int nt=0;nt<13;nt++){
    int qb = nt*16 + (l&15); if(qb > 196) qb = 196;
    short8 b0 = *(const short8*)(Qg + (size_t)qb*768 + zq);
    short8 b1 = *(const short8*)(Qg + (size_t)qb*768 + 32 + zq);
    acc[nt] = __builtin_amdgcn_mfma_f32_16x16x32_bf16(aof0, b0, acc[nt], 0,0,0);
    acc[nt] = __builtin_amdgcn_mfma_f32_16x16x32_bf16(aof1, b1, acc[nt], 0,0,0);
  }
  #pragma unroll
  for(int nt=0;nt<13;nt++){
    int q = (l&15) + 16*nt;   // <= 207
    float m  = Mst[(size_t)bhl*208 + q];
    float il = Lst[(size_t)bhl*208 + q];
    #pragma unroll
    for(int r=0;r<4;r++) acc[nt][r] = __expf(ATT_BETA*(acc[nt][r]-m))*il;
  }
  #pragma unroll
  for(int r=0;r<4;r++){
    int j = j0 + (l>>4)*4 + r;
    if(j > 196) continue;
    size_t base = ((size_t)bhl*208 + j)*224;
    #pragma unroll
    for(int nt=0;nt<13;nt++) At[base + (l&15) + 16*nt] = f2bf(acc[nt][r]);
    At[base + 208 + (l&15)] = 0;
  }
}

// ---------------- attention apply: Gq = A K (waves 0,1) ; Gk = A^T Q (waves 2,3). Grid: chunk -
__global__ __launch_bounds__(256)
void av_k(const u16* __restrict__ A, const u16* __restrict__ At,
          u16* __restrict__ Qb, u16* __restrict__ Kb, int bh0)
{
  __shared__ u16 T[2*64*232];   // [0]=Kt[z][j], [1]=Qt[z][q]  (59,392 B)
  int bhl = blockIdx.x, bh = bh0 + bhl, b = bh/12, h = bh - b*12;
  u16* Qg = Qb + (size_t)b*197*768 + h*64;
  u16* Kg = Kb + (size_t)b*197*768 + h*64;
  int tid = threadIdx.x, w = tid>>6, l = tid&63;
  for(int idx=tid; idx<197*64; idx+=256){
    int j = idx>>6, z = idx&63;
    T[z*232 + j]           = Kg[(size_t)j*768 + z];
    T[64*232 + z*232 + j]  = Qg[(size_t)j*768 + z];
  }
  // zero LDS pad cols j=197..231: stale LDS bits can be NaN-pattern bf16; 0*NaN=NaN in MFMA
  for(int idx=tid; idx<35*64; idx+=256){
    int z = idx/35, j = 197 + (idx - z*35);
    T[z*232 + j] = 0;
    T[64*232 + z*232 + j] = 0;
  }
  __syncthreads();
  bool gq = (w < 2);
  int ww = w & 1;
  const u16* Aop = gq ? A : At;
  const u16* Bt  = gq ? T : (T + 64*232);
  u16* Og = gq ? Qg : Kg;
  int mt0 = ww*7, mcnt = ww ? 6 : 7;
  f32x4 acc[7][4];
  #pragma unroll
  for(int i=0;i<7;i++)
    #pragma unroll
    for(int n=0;n<4;n++) acc[i][n] = (f32x4){0.f,0.f,0.f,0.f};
  size_t abase = (size_t)bhl*208*224;
  for(int kt=0; kt<7; kt++){
    short8 bfv[4];
    int ko = kt*32 + (l>>4)*8;
    #pragma unroll
    for(int nt=0;nt<4;nt++) bfv[nt] = *(const short8*)&Bt[(nt*16 + (l&15))*232 + ko];
    for(int mi=0; mi<mcnt; mi++){
      int row = (mt0+mi)*16 + (l&15);
      short8 af = *(const short8*)(Aop + abase + (size_t)row*224 + ko);
      #pragma unroll
      for(int nt=0;nt<4;nt++)
        acc[mi][nt] = __builtin_amdgcn_mfma_f32_16x16x32_bf16(af, bfv[nt], acc[mi][nt], 0,0,0);
    }
  }
  for(int mi=0; mi<mcnt; mi++){
    #pragma unroll
    for(int nt=0;nt<4;nt++){
      #pragma unroll
      for(int r=0;r<4;r++){
        int row = (mt0+mi)*16 + (l>>4)*4 + r;
        if(row > 196) continue;
        Og[(size_t)row*768 + nt*16 + (l&15)] = f2bf(acc[mi][nt][r]);
      }
    }
  }
}

// ---------------- small utility kernels ----------------
__global__ void cvt_k(const float* __restrict__ in, u16* __restrict__ out, int n){
  for(int i=blockIdx.x*256+threadIdx.x; i<n; i+=gridDim.x*256) out[i] = f2bf(in[i]);
}

// dst[c*dstride + coff + r] = bf16(src[r*C + c]); R,C multiples of 32
__global__ __launch_bounds__(256)
void tr_k(const float* __restrict__ src, u16* __restrict__ dst, int R, int C, int dstride, int coff){
  __shared__ float tile[32][33];
  int c0 = blockIdx.x*32, r0 = blockIdx.y*32;
  int tx = threadIdx.x & 31, ty = threadIdx.x >> 5;
  for(int i=ty;i<32;i+=8) tile[i][tx] = src[(size_t)(r0+i)*C + c0 + tx];
  __syncthreads();
  for(int i=ty;i<32;i+=8) dst[(size_t)(c0+i)*dstride + coff + r0 + tx] = f2bf(tile[tx][i]);
}

__global__ void fill_cls_k(float* __restrict__ t, const float* __restrict__ cls, const float* __restrict__ pos){
  int b = blockIdx.x;
  for(int i=threadIdx.x;i<768;i+=256) t[(size_t)b*197*768 + i] = cls[i] + pos[i];
}

// ---------------- launch ----------------
extern "C" void kernel_launch(void* const* d_in, const int* in_sizes, int n_in,
                              void* d_out, int out_size, void* d_ws, size_t ws_size,
                              hipStream_t stream){
  const float* x      = (const float*)d_in[0];
  const float* W_enc  = (const float*)d_in[1];
  const float* b_enc  = (const float*)d_in[2];
  const float* cls    = (const float*)d_in[3];
  const float* pos    = (const float*)d_in[4];
  const float* gamma  = (const float*)d_in[5];
  const float* bias   = (const float*)d_in[6];
  const float* Wq     = (const float*)d_in[7];
  const float* Wk     = (const float*)d_in[8];
  const float* Whn    = (const float*)d_in[9];
  const float* araw   = (const float*)d_in[10];
  const float* ln_g   = (const float*)d_in[11];
  const float* ln_b   = (const float*)d_in[12];
  const float* W_dec  = (const float*)d_in[13];
  const float* b_dec  = (const float*)d_in[14];
  float* out = (float*)d_out;
  (void)in_sizes; (void)n_in; (void)out_size;

  const int M  = 64*197;   // 12608
  const int MX = 64*196;   // 12544

  // ---- base workspace: 96,829,440 bytes (known to fit from R2) ----
  char* p = (char*)d_ws;
  float* t  = (float*)p;             p += (size_t)M*768*4;
  u16*   g  = (u16*)p;               p += (size_t)M*768*2;
  u16*   Qb = (u16*)p;               p += (size_t)M*768*2;
  u16*   Kb = (u16*)p;               p += (size_t)M*768*2;
  size_t base = (size_t)(p - (char*)d_ws);
  if(base > ws_size) return;

  // ---- attention A/At/stats region: adaptive chunk (deterministic given ws_size) ----
  const size_t perbh = (size_t)208*224*2*2 + (size_t)208*4*2;  // A + At + M + L = 188,032 B
  size_t spare = (ws_size > base) ? (ws_size - base) : 0;
  int chunk; char* Areg;
  if(spare >= 768*perbh){ chunk = 768; Areg = (char*)d_ws + base; }
  else if(spare >= 384*perbh){ chunk = 384; Areg = (char*)d_ws + base; }
  else if(spare >= 192*perbh){ chunk = 192; Areg = (char*)d_ws + base; }
  else { chunk = 96; Areg = (char*)g; }   // overlay on g (dead during attention)
  u16*  Abuf  = (u16*)Areg;
  u16*  Atbuf = Abuf + (size_t)chunk*208*224;
  float* Mst  = (float*)(Atbuf + (size_t)chunk*208*224);
  float* Lst  = Mst + (size_t)chunk*208;
  int nch = 768 / chunk;

  // ---- weights live inside d_out (28.3 MB of 38.5 MB; fully dead before decode write) ----
  u16* Wall = (u16*)d_out;
  u16* Wqkb = Wall;               // 2 x [Wq(768 rows); Wk(768 rows)] x 768
  u16* WqkT = Wall + 2359296;     // 2 x 768 x [WqT | WkT] (stride 1536)
  u16* WhnT = Wall + 4718592;     // 2 x 3072 x 768
  u16* WhnB = Wall + 9437184;     // 2 x 768 x 3072 (row-major, ldb 3072)
  u16* xb    = Qb;                // encode-time overlay
  u16* WencT = Kb;                // encode-time overlay
  u16* WdecT = Kb;                // decode-time overlay

  // ---- weight prep ----
  for(int b=0;b<2;b++){
    cvt_k<<<512,256,0,stream>>>(Wq + (size_t)b*589824, Wqkb + (size_t)b*1179648, 589824);
    cvt_k<<<512,256,0,stream>>>(Wk + (size_t)b*589824, Wqkb + (size_t)b*1179648 + 589824, 589824);
    tr_k<<<dim3(24,24),256,0,stream>>>(Wq + (size_t)b*589824, WqkT + (size_t)b*1179648, 768,768, 1536, 0);
    tr_k<<<dim3(24,24),256,0,stream>>>(Wk + (size_t)b*589824, WqkT + (size_t)b*1179648, 768,768, 1536, 768);
    tr_k<<<dim3(96,24),256,0,stream>>>(Whn + (size_t)b*2359296, WhnT + (size_t)b*2359296, 768,3072, 768, 0);
    cvt_k<<<2048,256,0,stream>>>(Whn + (size_t)b*2359296, WhnB + (size_t)b*2359296, 2359296);
  }

  // ---- encode: t = [cls; x@W_enc + b_enc] + pos ----
  cvt_k<<<1024,256,0,stream>>>(x, xb, MX*768);
  tr_k<<<dim3(24,24),256,0,stream>>>(W_enc, WencT, 768,768, 768, 0);
  fill_cls_k<<<64,256,0,stream>>>(t, cls, pos);
  gemm_bt<3,0><<<dim3(6,98),256,0,stream>>>(xb, nullptr, WencT, nullptr, nullptr, t,
                                            MX, 768, 768, 768, b_enc, pos, nullptr, 0);

  // ---- energy-descent blocks ----
  for(int blk=0; blk<2; blk++){
    for(int s=0; s<4; s++){
      norm_k<<<M,256,0,stream>>>(t, g, gamma, bias, blk, 0);
      // Hopfield (uses Qb as hidden scratch, before Q exists)
      for(int c=0;c<4;c++){
        gemm_bt<1,0><<<dim3(6,99),256,0,stream>>>(g, nullptr,
            WhnT + (size_t)blk*2359296 + (size_t)c*589824,
            Qb, nullptr, nullptr, M, 768, 768, 768, nullptr, nullptr, nullptr, 0);
        gemm_bt<2,0><<<dim3(6,99),256,0,stream>>>(Qb, nullptr,
            WhnB + (size_t)blk*2359296 + (size_t)c*768,
            nullptr, nullptr, t, M, 768, 768, 3072, nullptr, nullptr, araw, blk);
      }
      // Q,K projection (merged, dual-store)
      gemm_bt<5,0><<<dim3(12,99),256,0,stream>>>(g, nullptr, Wqkb + (size_t)blk*1179648,
            Qb, Kb, nullptr, M, 1536, 768, 768, nullptr, nullptr, nullptr, 0);
      // attention (chunked; A/At overlay g when ws is small — g is dead here)
      for(int c=0;c<nch;c++){
        int bh0 = c*chunk;
        scores_k <<<chunk*4,256,0,stream>>>(Qb, Kb, Abuf, Mst, Lst, bh0);
        scoresT_k<<<chunk*4,256,0,stream>>>(Qb, Kb, Atbuf, Mst, Lst, bh0);
        av_k     <<<chunk,  256,0,stream>>>(Abuf, Atbuf, Qb, Kb, bh0);
      }
      // gradient projection (merged K=1536, split-A)
      gemm_bt<2,1><<<dim3(6,99),256,0,stream>>>(Qb, Kb, WqkT + (size_t)blk*1179648,
            nullptr, nullptr, t, M, 768, 1536, 1536, nullptr, nullptr, araw, blk);
    }
  }

  // ---- decode: LN -> GEMM -> drop CLS ----
  tr_k<<<dim3(24,24),256,0,stream>>>(W_dec, WdecT, 768,768, 768, 0);
  norm_k<<<M,256,0,stream>>>(t, g, ln_g, ln_b, 0, 1);
  gemm_bt<4,0><<<dim3(6,99),256,0,stream>>>(g, nullptr, WdecT, nullptr, nullptr, out,
                                            M, 768, 768, 768, b_dec, nullptr, nullptr, 0);
}

// Round 5
// 5402.533 us; speedup vs baseline: 5.2974x; 1.4598x over previous
//
#include <hip/hip_runtime.h>
#include <cstdint>
#include <cstddef>

using u16 = unsigned short;
typedef short short8 __attribute__((ext_vector_type(8)));
typedef float f32x4 __attribute__((ext_vector_type(4)));

#define LN_EPS 1e-5f
#define ATT_BETA 0.125f

__device__ __forceinline__ u16 f2bf(float f){
  uint32_t u = __float_as_uint(f);
  u += 0x7fffu + ((u >> 16) & 1u);
  return (u16)(u >> 16);
}
__device__ __forceinline__ float bf2f(u16 h){
  return __uint_as_float(((uint32_t)h) << 16);
}
__device__ __forceinline__ float wred_sum(float v){
  #pragma unroll
  for(int o=32;o;o>>=1) v += __shfl_xor(v,o,64);
  return v;
}
__device__ __forceinline__ void async16(const void* g, void* l){
  __builtin_amdgcn_global_load_lds((const __attribute__((address_space(1))) void*)g,
                                   (__attribute__((address_space(3))) void*)l, 16, 0, 0);
}

// ---------------- generic bf16 MFMA GEMM: C[M,N] = A[M,K] * B[N,K]^T (B row stride ldb) -------
// EPI: 1=bf16+relu out (row stride ldc), 2=t += alpha*acc, 3=encode epilogue, 4=decode epilogue,
//      5=dual store + transposed stores: col<768 -> Cb & QTo, col>=768 -> Cb2 & KTo
// ASPL: A operand split: k<768 from A, k>=768 from A2 (both row stride 768)
template<int EPI, int ASPL>
__global__ __launch_bounds__(256)
void gemm_bt(const u16* __restrict__ A, const u16* __restrict__ A2,
             const u16* __restrict__ B,
             u16* __restrict__ Cb, u16* __restrict__ Cb2, float* __restrict__ Cf,
             int M, int N, int K, int ldb, int ldc,
             u16* __restrict__ QTo, u16* __restrict__ KTo,
             const float* __restrict__ aux0, const float* __restrict__ aux1,
             const float* __restrict__ araw, int blk)
{
  __shared__ u16 lA[128*32];
  __shared__ u16 lB[128*32];
  int tid = threadIdx.x;
  int w = tid >> 6, l = tid & 63;
  int wm = w >> 1, wn = w & 1;
  int m0 = blockIdx.y * 128, n0 = blockIdx.x * 128;
  int lr = l >> 2;           // row within 16-row chunk
  int lc = (l & 3) * 8;      // col (elements) within 32-wide K slab
  f32x4 acc[4][4];
  #pragma unroll
  for(int i=0;i<4;i++)
    #pragma unroll
    for(int j=0;j<4;j++) acc[i][j] = (f32x4){0.f,0.f,0.f,0.f};
  int fm = l & 15, fq = (l >> 4) * 8;

  for(int kt=0; kt<K; kt+=32){
    __syncthreads();
    const u16* Asrc = A; int kcol = kt;
    if(ASPL){ if(kt >= 768){ Asrc = A2; kcol = kt - 768; } }
    int lda = ASPL ? 768 : K;
    #pragma unroll
    for(int c=0;c<2;c++){
      int rr = (w*2+c)*16;
      int ga = m0 + rr + lr; if(ga > M-1) ga = M-1;
      async16(Asrc + (size_t)ga*lda + kcol + lc, &lA[rr*32]);
      int gb = n0 + rr + lr; if(gb > N-1) gb = N-1;
      async16(B + (size_t)gb*ldb + kt + lc, &lB[rr*32]);
    }
    __syncthreads();
    short8 af[4], bfv[4];
    #pragma unroll
    for(int i=0;i<4;i++) af[i]  = *(const short8*)&lA[(wm*64 + i*16 + fm)*32 + fq];
    #pragma unroll
    for(int j=0;j<4;j++) bfv[j] = *(const short8*)&lB[(wn*64 + j*16 + fm)*32 + fq];
    #pragma unroll
    for(int i=0;i<4;i++)
      #pragma unroll
      for(int j=0;j<4;j++)
        acc[i][j] = __builtin_amdgcn_mfma_f32_16x16x32_bf16(af[i], bfv[j], acc[i][j], 0, 0, 0);
  }

  float alpha = 0.f;
  if(EPI==2) alpha = log1pf(__expf(araw[blk]));

  #pragma unroll
  for(int i=0;i<4;i++){
    int row_b = m0 + wm*64 + i*16 + (l>>4)*4;
    #pragma unroll
    for(int j=0;j<4;j++){
      int col = n0 + wn*64 + j*16 + (l&15);
      #pragma unroll
      for(int r=0;r<4;r++){
        int row = row_b + r;
        if(row >= M) continue;
        float v = acc[i][j][r];
        if(EPI==1){
          Cb[(size_t)row*ldc + col] = f2bf(v > 0.f ? v : 0.f);
        } else if(EPI==2){
          Cf[(size_t)row*768 + col] += alpha * v;
        } else if(EPI==3){
          int pb = row / 196, pn = row - pb*196;
          Cf[((size_t)pb*197 + 1 + pn)*768 + col] = v + aux0[col] + aux1[(size_t)(1+pn)*768 + col];
        } else if(EPI==4){
          int pb = row / 197, rr2 = row - pb*197;
          if(rr2 > 0) Cf[((size_t)pb*196 + rr2 - 1)*768 + col] = v + aux0[col];
        } else { // EPI==5
          unsigned rw = (unsigned)row;
          unsigned pb = rw / 197u, jl = rw - pb*197u;
          u16 hv = f2bf(v);
          if(col < 768){
            Cb[(size_t)row*768 + col] = hv;
            QTo[(size_t)(pb*12u + (unsigned)(col>>6))*14336 + (size_t)(col&63)*224 + jl] = hv;
          } else {
            int c2 = col - 768;
            Cb2[(size_t)row*768 + c2] = hv;
            KTo[(size_t)(pb*12u + (unsigned)(c2>>6))*14336 + (size_t)(c2&63)*224 + jl] = hv;
          }
        }
      }
    }
  }
}

// ---------------- LN: mode 0 = EnergyLN (scalar gamma + per-dim bias), 1 = final LN ----------
__global__ __launch_bounds__(256)
void norm_k(const float* __restrict__ t, u16* __restrict__ out,
            const float* __restrict__ gv, const float* __restrict__ bv, int blk, int mode)
{
  __shared__ float r1[4], r2[4];
  int row = blockIdx.x;
  const float* tr = t + (size_t)row*768;
  int tid = threadIdx.x, w = tid>>6, l = tid&63;
  float s=0.f, s2=0.f;
  for(int i=tid;i<768;i+=256){ float v = tr[i]; s += v; s2 += v*v; }
  s = wred_sum(s); s2 = wred_sum(s2);
  if(l==0){ r1[w]=s; r2[w]=s2; }
  __syncthreads();
  s  = r1[0]+r1[1]+r1[2]+r1[3];
  s2 = r2[0]+r2[1]+r2[2]+r2[3];
  float mu  = s * (1.0f/768.0f);
  float var = s2 * (1.0f/768.0f) - mu*mu;
  float rs  = rsqrtf(var + LN_EPS);
  u16* orow = out + (size_t)row*768;
  if(mode==0){
    float gm = gv[blk];
    const float* bb = bv + blk*768;
    for(int i=tid;i<768;i+=256) orow[i] = f2bf((tr[i]-mu)*rs*gm + bb[i]);
  } else {
    for(int i=tid;i<768;i+=256) orow[i] = f2bf((tr[i]-mu)*rs*gv[i] + bv[i]);
  }
}

// ---------------- fused attention per (b,h). Grid 768 x 256 threads. --------------------------
// S = Q K^T stripewise (32 q-rows), softmax -> P in LDS (XOR-swizzled bf16), then
// Gq = P K   (B-frags from pre-transposed KT),  overwrites Qb rows in place
// Gk = P^T Q (B-frags from pre-transposed QT),  accumulated in regs, written to Kb at end
// P LDS layout: row q (0..31) x 256 u16; logical col j stored in 8-elem group (j>>3)^(q&7).
__global__ __launch_bounds__(256)
void attn_k(u16* __restrict__ Qb, u16* __restrict__ Kb,
            const u16* __restrict__ QT, const u16* __restrict__ KT)
{
  __shared__ u16 P[32*256];
  __shared__ float SredM[2][2][16];
  __shared__ float SredS[2][2][16];
  int bh = blockIdx.x, b = bh/12, h = bh - b*12;
  u16* Qg = Qb + (size_t)b*197*768 + h*64;
  u16* Kg = Kb + (size_t)b*197*768 + h*64;
  const u16* QTg = QT + (size_t)bh*14336;
  const u16* KTg = KT + (size_t)bh*14336;
  int tid = threadIdx.x, w = tid>>6, l = tid&63;
  int lane16 = l & 15, quad = l >> 4;
  int mt = w & 1, nh = w >> 1;
  int nt0 = nh*7, ncnt = nh ? 6 : 7;
  int jt0 = (w==0) ? 0 : (1 + 3*w);   // w0:{0..3} w1:{4..6} w2:{7..9} w3:{10..12}
  int jn  = (w==0) ? 4 : 3;

  f32x4 gk[4][4];
  #pragma unroll
  for(int a=0;a<4;a++)
    #pragma unroll
    for(int n2=0;n2<4;n2++) gk[a][n2] = (f32x4){0.f,0.f,0.f,0.f};

  for(int st=0; st<7; st++){
    int q0 = st*32;
    __syncthreads();   // protect P/Sred rewrite vs previous stripe readers
    // ---- scores stripe: rows q0+16*mt+lane16, cols nt*16+lane16
    int qa = q0 + 16*mt + lane16; if(qa > 196) qa = 196;
    short8 a0 = *(const short8*)(Qg + (size_t)qa*768 + quad*8);
    short8 a1 = *(const short8*)(Qg + (size_t)qa*768 + 32 + quad*8);
    f32x4 sa[7];
    #pragma unroll
    for(int ni=0;ni<7;ni++) sa[ni] = (f32x4){0.f,0.f,0.f,0.f};
    for(int ni=0; ni<ncnt; ni++){
      int jb = (nt0+ni)*16 + lane16; if(jb > 196) jb = 196;
      short8 b0 = *(const short8*)(Kg + (size_t)jb*768 + quad*8);
      short8 b1 = *(const short8*)(Kg + (size_t)jb*768 + 32 + quad*8);
      sa[ni] = __builtin_amdgcn_mfma_f32_16x16x32_bf16(a0, b0, sa[ni],0,0,0);
      sa[ni] = __builtin_amdgcn_mfma_f32_16x16x32_bf16(a1, b1, sa[ni],0,0,0);
    }
    // mask invalid cols
    for(int ni=0; ni<ncnt; ni++){
      if((nt0+ni)*16 + lane16 > 196){
        sa[ni][0]=-3e38f; sa[ni][1]=-3e38f; sa[ni][2]=-3e38f; sa[ni][3]=-3e38f;
      }
    }
    // row max (partial within wave's n-half, 16-lane shuffle)
    float mx[4] = {-3e38f,-3e38f,-3e38f,-3e38f};
    for(int ni=0; ni<ncnt; ni++)
      #pragma unroll
      for(int r=0;r<4;r++) mx[r] = fmaxf(mx[r], sa[ni][r]);
    #pragma unroll
    for(int o=1;o<16;o<<=1)
      #pragma unroll
      for(int r=0;r<4;r++) mx[r] = fmaxf(mx[r], __shfl_xor(mx[r], o, 64));
    if(lane16==0){
      #pragma unroll
      for(int r=0;r<4;r++) SredM[mt][nh][quad*4+r] = mx[r];
    }
    __syncthreads();
    float m2[4];
    #pragma unroll
    for(int r=0;r<4;r++) m2[r] = fmaxf(SredM[mt][0][quad*4+r], SredM[mt][1][quad*4+r]);
    float ss[4] = {0.f,0.f,0.f,0.f};
    for(int ni=0; ni<ncnt; ni++)
      #pragma unroll
      for(int r=0;r<4;r++){
        float e = __expf(ATT_BETA*(sa[ni][r]-m2[r]));
        sa[ni][r] = e; ss[r] += e;
      }
    #pragma unroll
    for(int o=1;o<16;o<<=1)
      #pragma unroll
      for(int r=0;r<4;r++) ss[r] += __shfl_xor(ss[r], o, 64);
    if(lane16==0){
      #pragma unroll
      for(int r=0;r<4;r++) SredS[mt][nh][quad*4+r] = ss[r];
    }
    __syncthreads();
    float inv[4];
    #pragma unroll
    for(int r=0;r<4;r++) inv[r] = 1.f/(SredS[mt][0][quad*4+r] + SredS[mt][1][quad*4+r]);
    // write P stripe (swizzled); rows q>196 forced 0 (avoids 0*inf NaN and Gk pollution)
    for(int ni=0; ni<ncnt; ni++){
      int j = (nt0+ni)*16 + lane16;
      #pragma unroll
      for(int r=0;r<4;r++){
        int q = 16*mt + quad*4 + r;
        float val = (q0 + q <= 196) ? sa[ni][r]*inv[r] : 0.f;
        P[q*256 + 8*((j>>3)^(q&7)) + (j&7)] = f2bf(val);
      }
    }
    // zero logical cols 208..223 (read by Gq kt=6 upper quads)
    for(int idx=tid; idx<32*16; idx+=256){
      int q = idx>>4, j = 208 + (idx&15);
      P[q*256 + 8*((j>>3)^(q&7)) + (j&7)] = 0;
    }
    __syncthreads();
    // ---- Gq = P K : out rows = stripe q, cols z; wave tile: mt x (nh*2 + {0,1})
    {
      f32x4 gq[2]; gq[0] = (f32x4){0.f,0.f,0.f,0.f}; gq[1] = gq[0];
      int np0 = nh*2;
      int qrow = 16*mt + lane16;
      for(int kt=0; kt<7; kt++){
        short8 af = *(const short8*)&P[qrow*256 + 8*((4*kt+quad)^(qrow&7))];
        #pragma unroll
        for(int n2=0;n2<2;n2++){
          int z = (np0+n2)*16 + lane16;
          short8 bf8 = *(const short8*)(KTg + (size_t)z*224 + kt*32 + quad*8);
          gq[n2] = __builtin_amdgcn_mfma_f32_16x16x32_bf16(af, bf8, gq[n2],0,0,0);
        }
      }
      #pragma unroll
      for(int n2=0;n2<2;n2++)
        #pragma unroll
        for(int r=0;r<4;r++){
          int qg2 = q0 + 16*mt + quad*4 + r;
          if(qg2 <= 196) Qg[(size_t)qg2*768 + (np0+n2)*16 + lane16] = f2bf(gq[n2][r]);
        }
    }
    // ---- Gk accumulate: A = P^T (strided LDS gather), B = Q^T (global contiguous)
    {
      short8 bq[4];
      #pragma unroll
      for(int n2=0;n2<4;n2++)
        bq[n2] = *(const short8*)(QTg + (size_t)(n2*16+lane16)*224 + q0 + quad*8);
      for(int ji=0; ji<jn; ji++){
        int jt = jt0 + ji;
        short8 af;
        #pragma unroll
        for(int i=0;i<8;i++){
          int q = quad*8 + i, j = jt*16 + lane16;
          af[i] = (short)P[q*256 + 8*((j>>3)^(q&7)) + (j&7)];
        }
        #pragma unroll
        for(int n2=0;n2<4;n2++)
          gk[ji][n2] = __builtin_amdgcn_mfma_f32_16x16x32_bf16(af, bq[n2], gk[ji][n2],0,0,0);
      }
    }
  }
  // ---- write Gk (all stripes' score reads of Kg are done: block-wide sync passed each stripe)
  __syncthreads();
  for(int ji=0; ji<jn; ji++){
    int jt = jt0 + ji;
    #pragma unroll
    for(int n2=0;n2<4;n2++)
      #pragma unroll
      for(int r=0;r<4;r++){
        int j = jt*16 + quad*4 + r;
        if(j <= 196) Kg[(size_t)j*768 + n2*16 + lane16] = f2bf(gk[ji][n2][r]);
      }
  }
}

// ---------------- small utility kernels ----------------
__global__ void cvt_k(const float* __restrict__ in, u16* __restrict__ out, int n){
  for(int i=blockIdx.x*256+threadIdx.x; i<n; i+=gridDim.x*256) out[i] = f2bf(in[i]);
}

// dst[c*dstride + coff + r] = bf16(src[r*C + c]); R,C multiples of 32
__global__ __launch_bounds__(256)
void tr_k(const float* __restrict__ src, u16* __restrict__ dst, int R, int C, int dstride, int coff){
  __shared__ float tile[32][33];
  int c0 = blockIdx.x*32, r0 = blockIdx.y*32;
  int tx = threadIdx.x & 31, ty = threadIdx.x >> 5;
  for(int i=ty;i<32;i+=8) tile[i][tx] = src[(size_t)(r0+i)*C + c0 + tx];
  __syncthreads();
  for(int i=ty;i<32;i+=8) dst[(size_t)(c0+i)*dstride + coff + r0 + tx] = f2bf(tile[tx][i]);
}

__global__ void fill_cls_k(float* __restrict__ t, const float* __restrict__ cls, const float* __restrict__ pos){
  int b = blockIdx.x;
  for(int i=threadIdx.x;i<768;i+=256) t[(size_t)b*197*768 + i] = cls[i] + pos[i];
}

// ---------------- launch ----------------
extern "C" void kernel_launch(void* const* d_in, const int* in_sizes, int n_in,
                              void* d_out, int out_size, void* d_ws, size_t ws_size,
                              hipStream_t stream){
  const float* x      = (const float*)d_in[0];
  const float* W_enc  = (const float*)d_in[1];
  const float* b_enc  = (const float*)d_in[2];
  const float* cls    = (const float*)d_in[3];
  const float* pos    = (const float*)d_in[4];
  const float* gamma  = (const float*)d_in[5];
  const float* bias   = (const float*)d_in[6];
  const float* Wq     = (const float*)d_in[7];
  const float* Wk     = (const float*)d_in[8];
  const float* Whn    = (const float*)d_in[9];
  const float* araw   = (const float*)d_in[10];
  const float* ln_g   = (const float*)d_in[11];
  const float* ln_b   = (const float*)d_in[12];
  const float* W_dec  = (const float*)d_in[13];
  const float* b_dec  = (const float*)d_in[14];
  float* out = (float*)d_out;
  (void)in_sizes; (void)n_in; (void)out_size;

  const int M  = 64*197;   // 12608
  const int MX = 64*196;   // 12544

  // ---- workspace: 140,869,632 B (R4 counters imply chunk=768 ran => ws >= ~241 MB) ----
  char* p = (char*)d_ws;
  float* t   = (float*)p;  p += (size_t)M*768*4;        // 38.7 MB
  u16*   g   = (u16*)p;    p += (size_t)M*768*2;        // 19.4 MB
  u16*   Qb  = (u16*)p;    p += (size_t)M*768*2;        // 19.4 MB (Q -> Gq; hop hidden lo; xb)
  u16*   Kb  = (u16*)p;    p += (size_t)M*768*2;        // 19.4 MB (K -> Gk; hop hidden hi; WencT/WdecT)
  u16*   QTb = (u16*)p;    p += (size_t)768*14336*2;    // 22.0 MB [bh][z][224] transposed Q
  u16*   KTb = (u16*)p;    p += (size_t)768*14336*2;    // 22.0 MB
  if((size_t)(p - (char*)d_ws) > ws_size) return;

  u16* hidden = Qb;        // hopfield scratch [M][1536] spans Qb+Kb (dead before projection)

  // ---- weights live inside d_out (28.3 MB of 38.5 MB; fully dead before decode write) ----
  u16* Wall = (u16*)d_out;
  u16* Wqkb = Wall;               // 2 x [Wq(768 rows); Wk(768 rows)] x 768
  u16* WqkT = Wall + 2359296;     // 2 x 768 x [WqT | WkT] (stride 1536)
  u16* WhnT = Wall + 4718592;     // 2 x 3072 x 768
  u16* WhnB = Wall + 9437184;     // 2 x 768 x 3072 (row-major, ldb 3072)
  u16* xb    = Qb;                // encode-time overlay
  u16* WencT = Kb;                // encode-time overlay
  u16* WdecT = Kb;                // decode-time overlay

  // ---- weight prep ----
  for(int b=0;b<2;b++){
    cvt_k<<<512,256,0,stream>>>(Wq + (size_t)b*589824, Wqkb + (size_t)b*1179648, 589824);
    cvt_k<<<512,256,0,stream>>>(Wk + (size_t)b*589824, Wqkb + (size_t)b*1179648 + 589824, 589824);
    tr_k<<<dim3(24,24),256,0,stream>>>(Wq + (size_t)b*589824, WqkT + (size_t)b*1179648, 768,768, 1536, 0);
    tr_k<<<dim3(24,24),256,0,stream>>>(Wk + (size_t)b*589824, WqkT + (size_t)b*1179648, 768,768, 1536, 768);
    tr_k<<<dim3(96,24),256,0,stream>>>(Whn + (size_t)b*2359296, WhnT + (size_t)b*2359296, 768,3072, 768, 0);
    cvt_k<<<2048,256,0,stream>>>(Whn + (size_t)b*2359296, WhnB + (size_t)b*2359296, 2359296);
  }

  // ---- encode: t = [cls; x@W_enc + b_enc] + pos ----
  cvt_k<<<1024,256,0,stream>>>(x, xb, MX*768);
  tr_k<<<dim3(24,24),256,0,stream>>>(W_enc, WencT, 768,768, 768, 0);
  fill_cls_k<<<64,256,0,stream>>>(t, cls, pos);
  gemm_bt<3,0><<<dim3(6,98),256,0,stream>>>(xb, nullptr, WencT, nullptr, nullptr, t,
                                            MX, 768, 768, 768, 768, nullptr, nullptr,
                                            b_enc, pos, nullptr, 0);

  // ---- energy-descent blocks ----
  for(int blk=0; blk<2; blk++){
    for(int s=0; s<4; s++){
      norm_k<<<M,256,0,stream>>>(t, g, gamma, bias, blk, 0);
      // Hopfield in 2 chunks of N=1536 (hidden scratch = Qb+Kb, before Q/K exist)
      for(int c=0;c<2;c++){
        gemm_bt<1,0><<<dim3(12,99),256,0,stream>>>(g, nullptr,
            WhnT + (size_t)blk*2359296 + (size_t)c*1536*768,
            hidden, nullptr, nullptr, M, 1536, 768, 768, 1536, nullptr, nullptr,
            nullptr, nullptr, nullptr, 0);
        gemm_bt<2,0><<<dim3(6,99),256,0,stream>>>(hidden, nullptr,
            WhnB + (size_t)blk*2359296 + (size_t)c*1536,
            nullptr, nullptr, t, M, 768, 1536, 3072, 768, nullptr, nullptr,
            nullptr, nullptr, araw, blk);
      }
      // Q,K projection (dual store row-major + transposed QT/KT)
      gemm_bt<5,0><<<dim3(12,99),256,0,stream>>>(g, nullptr, Wqkb + (size_t)blk*1179648,
            Qb, Kb, nullptr, M, 1536, 768, 768, 768, QTb, KTb,
            nullptr, nullptr, nullptr, 0);
      // fused attention: Qb := Gq, Kb := Gk (in place)
      attn_k<<<768,256,0,stream>>>(Qb, Kb, QTb, KTb);
      // gradient projection (merged K=1536, split-A)
      gemm_bt<2,1><<<dim3(6,99),256,0,stream>>>(Qb, Kb, WqkT + (size_t)blk*1179648,
            nullptr, nullptr, t, M, 768, 1536, 1536, 768, nullptr, nullptr,
            nullptr, nullptr, araw, blk);
    }
  }

  // ---- decode: LN -> GEMM -> drop CLS ----
  tr_k<<<dim3(24,24),256,0,stream>>>(W_dec, WdecT, 768,768, 768, 0);
  norm_k<<<M,256,0,stream>>>(t, g, ln_g, ln_b, 0, 1);
  gemm_bt<4,0><<<dim3(6,99),256,0,stream>>>(g, nullptr, WdecT, nullptr, nullptr, out,
                                            M, 768, 768, 768, 768, nullptr, nullptr,
                                            b_dec, nullptr, nullptr, 0);
}

// Round 6
// 5148.594 us; speedup vs baseline: 5.5587x; 1.0493x over previous
//
#include <hip/hip_runtime.h>
#include <cstdint>
#include <cstddef>

using u16 = unsigned short;
typedef short short8 __attribute__((ext_vector_type(8)));
typedef short short4v __attribute__((ext_vector_type(4)));
typedef float f32x4 __attribute__((ext_vector_type(4)));

#define LN_EPS 1e-5f
#define ATT_BETA 0.125f

__device__ __forceinline__ u16 f2bf(float f){
  uint32_t u = __float_as_uint(f);
  u += 0x7fffu + ((u >> 16) & 1u);
  return (u16)(u >> 16);
}
__device__ __forceinline__ float bf2f(u16 h){
  return __uint_as_float(((uint32_t)h) << 16);
}
__device__ __forceinline__ float wred_sum(float v){
  #pragma unroll
  for(int o=32;o;o>>=1) v += __shfl_xor(v,o,64);
  return v;
}
__device__ __forceinline__ void async16(const void* g, void* l){
  __builtin_amdgcn_global_load_lds((const __attribute__((address_space(1))) void*)g,
                                   (__attribute__((address_space(3))) void*)l, 16, 0, 0);
}

// ---------------- generic bf16 MFMA GEMM: C[M,N] = A[M,K] * B[N,K]^T (B row stride ldb) -------
// EPI: 1=bf16+relu out (row stride ldc), 2=t += alpha*acc, 3=encode epilogue, 4=decode epilogue,
//      5=dual store + transposed stores: col<768 -> Cb & QTo, col>=768 -> Cb2 & KTo
// ASPL: A operand split: k<768 from A, k>=768 from A2 (both row stride 768)
template<int EPI, int ASPL>
__global__ __launch_bounds__(256)
void gemm_bt(const u16* __restrict__ A, const u16* __restrict__ A2,
             const u16* __restrict__ B,
             u16* __restrict__ Cb, u16* __restrict__ Cb2, float* __restrict__ Cf,
             int M, int N, int K, int ldb, int ldc,
             u16* __restrict__ QTo, u16* __restrict__ KTo,
             const float* __restrict__ aux0, const float* __restrict__ aux1,
             const float* __restrict__ araw, int blk)
{
  __shared__ u16 lA[128*32];
  __shared__ u16 lB[128*32];
  int tid = threadIdx.x;
  int w = tid >> 6, l = tid & 63;
  int wm = w >> 1, wn = w & 1;
  int m0 = blockIdx.y * 128, n0 = blockIdx.x * 128;
  int lr = l >> 2;           // row within 16-row chunk
  int lc = (l & 3) * 8;      // col (elements) within 32-wide K slab
  f32x4 acc[4][4];
  #pragma unroll
  for(int i=0;i<4;i++)
    #pragma unroll
    for(int j=0;j<4;j++) acc[i][j] = (f32x4){0.f,0.f,0.f,0.f};
  int fm = l & 15, fq = (l >> 4) * 8;

  for(int kt=0; kt<K; kt+=32){
    __syncthreads();
    const u16* Asrc = A; int kcol = kt;
    if(ASPL){ if(kt >= 768){ Asrc = A2; kcol = kt - 768; } }
    int lda = ASPL ? 768 : K;
    #pragma unroll
    for(int c=0;c<2;c++){
      int rr = (w*2+c)*16;
      int ga = m0 + rr + lr; if(ga > M-1) ga = M-1;
      async16(Asrc + (size_t)ga*lda + kcol + lc, &lA[rr*32]);
      int gb = n0 + rr + lr; if(gb > N-1) gb = N-1;
      async16(B + (size_t)gb*ldb + kt + lc, &lB[rr*32]);
    }
    __syncthreads();
    short8 af[4], bfv[4];
    #pragma unroll
    for(int i=0;i<4;i++) af[i]  = *(const short8*)&lA[(wm*64 + i*16 + fm)*32 + fq];
    #pragma unroll
    for(int j=0;j<4;j++) bfv[j] = *(const short8*)&lB[(wn*64 + j*16 + fm)*32 + fq];
    #pragma unroll
    for(int i=0;i<4;i++)
      #pragma unroll
      for(int j=0;j<4;j++)
        acc[i][j] = __builtin_amdgcn_mfma_f32_16x16x32_bf16(af[i], bfv[j], acc[i][j], 0, 0, 0);
  }

  float alpha = 0.f;
  if(EPI==2) alpha = log1pf(__expf(araw[blk]));

  #pragma unroll
  for(int i=0;i<4;i++){
    int row_b = m0 + wm*64 + i*16 + (l>>4)*4;
    #pragma unroll
    for(int j=0;j<4;j++){
      int col = n0 + wn*64 + j*16 + (l&15);
      #pragma unroll
      for(int r=0;r<4;r++){
        int row = row_b + r;
        if(row >= M) continue;
        float v = acc[i][j][r];
        if(EPI==1){
          Cb[(size_t)row*ldc + col] = f2bf(v > 0.f ? v : 0.f);
        } else if(EPI==2){
          Cf[(size_t)row*768 + col] += alpha * v;
        } else if(EPI==3){
          int pb = row / 196, pn = row - pb*196;
          Cf[((size_t)pb*197 + 1 + pn)*768 + col] = v + aux0[col] + aux1[(size_t)(1+pn)*768 + col];
        } else if(EPI==4){
          int pb = row / 197, rr2 = row - pb*197;
          if(rr2 > 0) Cf[((size_t)pb*196 + rr2 - 1)*768 + col] = v + aux0[col];
        } else { // EPI==5
          unsigned rw = (unsigned)row;
          unsigned pb = rw / 197u, jl = rw - pb*197u;
          u16 hv = f2bf(v);
          if(col < 768){
            Cb[(size_t)row*768 + col] = hv;
            QTo[(size_t)(pb*12u + (unsigned)(col>>6))*14336 + (size_t)(col&63)*224 + jl] = hv;
          } else {
            int c2 = col - 768;
            Cb2[(size_t)row*768 + c2] = hv;
            KTo[(size_t)(pb*12u + (unsigned)(c2>>6))*14336 + (size_t)(c2&63)*224 + jl] = hv;
          }
        }
      }
    }
  }
}

// ---------------- LN: mode 0 = EnergyLN (scalar gamma + per-dim bias), 1 = final LN ----------
__global__ __launch_bounds__(256)
void norm_k(const float* __restrict__ t, u16* __restrict__ out,
            const float* __restrict__ gv, const float* __restrict__ bv, int blk, int mode)
{
  __shared__ float r1[4], r2[4];
  int row = blockIdx.x;
  const float* tr = t + (size_t)row*768;
  int tid = threadIdx.x, w = tid>>6, l = tid&63;
  float s=0.f, s2=0.f;
  for(int i=tid;i<768;i+=256){ float v = tr[i]; s += v; s2 += v*v; }
  s = wred_sum(s); s2 = wred_sum(s2);
  if(l==0){ r1[w]=s; r2[w]=s2; }
  __syncthreads();
  s  = r1[0]+r1[1]+r1[2]+r1[3];
  s2 = r2[0]+r2[1]+r2[2]+r2[3];
  float mu  = s * (1.0f/768.0f);
  float var = s2 * (1.0f/768.0f) - mu*mu;
  float rs  = rsqrtf(var + LN_EPS);
  u16* orow = out + (size_t)row*768;
  if(mode==0){
    float gm = gv[blk];
    const float* bb = bv + blk*768;
    for(int i=tid;i<768;i+=256) orow[i] = f2bf((tr[i]-mu)*rs*gm + bb[i]);
  } else {
    for(int i=tid;i<768;i+=256) orow[i] = f2bf((tr[i]-mu)*rs*gv[i] + bv[i]);
  }
}

// ---------------- fused attention per (b,h). Grid 768 x 256 threads. --------------------------
// S = Q K^T stripewise (32 q-rows), no-max softmax (beta=0.125, logits bounded; arg clamped),
// P kept in LDS in BOTH layouts: P[q][j] (swizzled, for Gq A-frags) and PT[j][q] (stride 40,
// written as packed b64 from the scores D-layout, read as b128 A-frags for Gk).
// Gq = P K (B-frags from KT) overwrites Qb in place; Gk = P^T Q (B-frags from QT) -> Kb at end.
__global__ __launch_bounds__(256)
void attn_k(u16* __restrict__ Qb, u16* __restrict__ Kb,
            const u16* __restrict__ QT, const u16* __restrict__ KT)
{
  __shared__ u16 P[32*256];      // 16,384 B
  __shared__ u16 PT[224*40];     // 17,920 B  (rows j=0..223, q stride 1, row stride 40)
  __shared__ float SredS[2][2][16];
  int bh = blockIdx.x, b = bh/12, h = bh - b*12;
  u16* Qg = Qb + (size_t)b*197*768 + h*64;
  u16* Kg = Kb + (size_t)b*197*768 + h*64;
  const u16* QTg = QT + (size_t)bh*14336;
  const u16* KTg = KT + (size_t)bh*14336;
  int tid = threadIdx.x, w = tid>>6, l = tid&63;
  int lane16 = l & 15, quad = l >> 4;
  int mt = w & 1, nh = w >> 1;
  int nt0 = nh*7, ncnt = nh ? 6 : 7;
  int jt0 = (w==0) ? 0 : (1 + 3*w);   // w0:{0..3} w1:{4..6} w2:{7..9} w3:{10..12}
  int jn  = (w==0) ? 4 : 3;

  f32x4 gk[4][4];
  #pragma unroll
  for(int a=0;a<4;a++)
    #pragma unroll
    for(int n2=0;n2<4;n2++) gk[a][n2] = (f32x4){0.f,0.f,0.f,0.f};

  for(int st=0; st<7; st++){
    int q0 = st*32;
    __syncthreads();   // protect P/PT/SredS rewrite vs previous stripe readers
    // ---- scores stripe: rows q0+16*mt+lane16, cols nt*16+lane16
    int qa = q0 + 16*mt + lane16; if(qa > 196) qa = 196;
    short8 a0 = *(const short8*)(Qg + (size_t)qa*768 + quad*8);
    short8 a1 = *(const short8*)(Qg + (size_t)qa*768 + 32 + quad*8);
    f32x4 sa[7];
    #pragma unroll
    for(int ni=0;ni<7;ni++) sa[ni] = (f32x4){0.f,0.f,0.f,0.f};
    for(int ni=0; ni<ncnt; ni++){
      int jb = (nt0+ni)*16 + lane16; if(jb > 196) jb = 196;
      short8 b0 = *(const short8*)(Kg + (size_t)jb*768 + quad*8);
      short8 b1 = *(const short8*)(Kg + (size_t)jb*768 + 32 + quad*8);
      sa[ni] = __builtin_amdgcn_mfma_f32_16x16x32_bf16(a0, b0, sa[ni],0,0,0);
      sa[ni] = __builtin_amdgcn_mfma_f32_16x16x32_bf16(a1, b1, sa[ni],0,0,0);
    }
    // mask invalid cols (exp(-huge)=0)
    for(int ni=0; ni<ncnt; ni++){
      if((nt0+ni)*16 + lane16 > 196){
        sa[ni][0]=-3e38f; sa[ni][1]=-3e38f; sa[ni][2]=-3e38f; sa[ni][3]=-3e38f;
      }
    }
    // no-max softmax: exp + partial row sums (within nh half), clamp arg for safety
    float ss[4] = {0.f,0.f,0.f,0.f};
    for(int ni=0; ni<ncnt; ni++)
      #pragma unroll
      for(int r=0;r<4;r++){
        float e = __expf(fminf(ATT_BETA*sa[ni][r], 80.f));
        sa[ni][r] = e; ss[r] += e;
      }
    #pragma unroll
    for(int o=1;o<16;o<<=1)
      #pragma unroll
      for(int r=0;r<4;r++) ss[r] += __shfl_xor(ss[r], o, 64);
    if(lane16==0){
      #pragma unroll
      for(int r=0;r<4;r++) SredS[mt][nh][quad*4+r] = ss[r];
    }
    __syncthreads();
    float inv[4];
    #pragma unroll
    for(int r=0;r<4;r++) inv[r] = 1.f/(SredS[mt][0][quad*4+r] + SredS[mt][1][quad*4+r]);
    // write P (row-major swizzled scalar) + PT (packed b64); rows q>196 forced 0
    for(int ni=0; ni<ncnt; ni++){
      int j = (nt0+ni)*16 + lane16;
      short4v pk;
      #pragma unroll
      for(int r=0;r<4;r++){
        int q = 16*mt + quad*4 + r;
        float val = (q0 + q <= 196) ? sa[ni][r]*inv[r] : 0.f;
        u16 hv = f2bf(val);
        P[q*256 + 8*((j>>3)^(q&7)) + (j&7)] = hv;
        pk[r] = (short)hv;
      }
      *(short4v*)&PT[j*40 + 16*mt + 4*quad] = pk;
    }
    // zero P logical cols 208..223 (read by Gq kt=6 upper quads)
    for(int idx=tid; idx<32*16; idx+=256){
      int q = idx>>4, j = 208 + (idx&15);
      P[q*256 + 8*((j>>3)^(q&7)) + (j&7)] = 0;
    }
    __syncthreads();
    // ---- Gq = P K : out rows = stripe q, cols z; wave tile: mt x (nh*2 + {0,1})
    {
      f32x4 gq[2]; gq[0] = (f32x4){0.f,0.f,0.f,0.f}; gq[1] = gq[0];
      int np0 = nh*2;
      int qrow = 16*mt + lane16;
      for(int kt=0; kt<7; kt++){
        short8 af = *(const short8*)&P[qrow*256 + 8*((4*kt+quad)^(qrow&7))];
        #pragma unroll
        for(int n2=0;n2<2;n2++){
          int z = (np0+n2)*16 + lane16;
          short8 bf8 = *(const short8*)(KTg + (size_t)z*224 + kt*32 + quad*8);
          gq[n2] = __builtin_amdgcn_mfma_f32_16x16x32_bf16(af, bf8, gq[n2],0,0,0);
        }
      }
      #pragma unroll
      for(int n2=0;n2<2;n2++)
        #pragma unroll
        for(int r=0;r<4;r++){
          int qg2 = q0 + 16*mt + quad*4 + r;
          if(qg2 <= 196) Qg[(size_t)qg2*768 + (np0+n2)*16 + lane16] = f2bf(gq[n2][r]);
        }
    }
    // ---- Gk accumulate: A-frags = contiguous b128 from PT, B-frags = Q^T (global contiguous)
    {
      short8 bq[4];
      #pragma unroll
      for(int n2=0;n2<4;n2++)
        bq[n2] = *(const short8*)(QTg + (size_t)(n2*16+lane16)*224 + q0 + quad*8);
      for(int ji=0; ji<jn; ji++){
        int j = (jt0+ji)*16 + lane16;
        short8 af = *(const short8*)&PT[j*40 + quad*8];
        #pragma unroll
        for(int n2=0;n2<4;n2++)
          gk[ji][n2] = __builtin_amdgcn_mfma_f32_16x16x32_bf16(af, bq[n2], gk[ji][n2],0,0,0);
      }
    }
  }
  // ---- write Gk (all scores reads of Kg completed before last stripe's compute barrier)
  __syncthreads();
  for(int ji=0; ji<jn; ji++){
    int jt = jt0 + ji;
    #pragma unroll
    for(int n2=0;n2<4;n2++)
      #pragma unroll
      for(int r=0;r<4;r++){
        int j = jt*16 + quad*4 + r;
        if(j <= 196) Kg[(size_t)j*768 + n2*16 + lane16] = f2bf(gk[ji][n2][r]);
      }
  }
}

// ---------------- small utility kernels ----------------
__global__ void cvt_k(const float* __restrict__ in, u16* __restrict__ out, int n){
  for(int i=blockIdx.x*256+threadIdx.x; i<n; i+=gridDim.x*256) out[i] = f2bf(in[i]);
}

// dst[c*dstride + coff + r] = bf16(src[r*C + c]); R,C multiples of 32
__global__ __launch_bounds__(256)
void tr_k(const float* __restrict__ src, u16* __restrict__ dst, int R, int C, int dstride, int coff){
  __shared__ float tile[32][33];
  int c0 = blockIdx.x*32, r0 = blockIdx.y*32;
  int tx = threadIdx.x & 31, ty = threadIdx.x >> 5;
  for(int i=ty;i<32;i+=8) tile[i][tx] = src[(size_t)(r0+i)*C + c0 + tx];
  __syncthreads();
  for(int i=ty;i<32;i+=8) dst[(size_t)(c0+i)*dstride + coff + r0 + tx] = f2bf(tile[tx][i]);
}

__global__ void fill_cls_k(float* __restrict__ t, const float* __restrict__ cls, const float* __restrict__ pos){
  int b = blockIdx.x;
  for(int i=threadIdx.x;i<768;i+=256) t[(size_t)b*197*768 + i] = cls[i] + pos[i];
}

// ---------------- launch ----------------
extern "C" void kernel_launch(void* const* d_in, const int* in_sizes, int n_in,
                              void* d_out, int out_size, void* d_ws, size_t ws_size,
                              hipStream_t stream){
  const float* x      = (const float*)d_in[0];
  const float* W_enc  = (const float*)d_in[1];
  const float* b_enc  = (const float*)d_in[2];
  const float* cls    = (const float*)d_in[3];
  const float* pos    = (const float*)d_in[4];
  const float* gamma  = (const float*)d_in[5];
  const float* bias   = (const float*)d_in[6];
  const float* Wq     = (const float*)d_in[7];
  const float* Wk     = (const float*)d_in[8];
  const float* Whn    = (const float*)d_in[9];
  const float* araw   = (const float*)d_in[10];
  const float* ln_g   = (const float*)d_in[11];
  const float* ln_b   = (const float*)d_in[12];
  const float* W_dec  = (const float*)d_in[13];
  const float* b_dec  = (const float*)d_in[14];
  float* out = (float*)d_out;
  (void)in_sizes; (void)n_in; (void)out_size;

  const int M  = 64*197;   // 12608
  const int MX = 64*196;   // 12544

  // ---- workspace (R4 counters proved ws >= 241.3 MB: chunk=768 path ran) ----
  char* p = (char*)d_ws;
  float* t   = (float*)p;  p += (size_t)M*768*4;        // 38.7 MB
  u16*   g   = (u16*)p;    p += (size_t)M*768*2;        // 19.4 MB
  u16*   Qb  = (u16*)p;    p += (size_t)M*768*2;        // 19.4 MB (Q -> Gq; xb overlay)
  u16*   Kb  = (u16*)p;    p += (size_t)M*768*2;        // 19.4 MB (K -> Gk; WencT/WdecT overlay)
  u16*   QTb = (u16*)p;    p += (size_t)768*14336*2;    // 22.0 MB [bh][z][224]
  u16*   KTb = (u16*)p;    p += (size_t)768*14336*2;    // 22.0 MB
  size_t base = (size_t)(p - (char*)d_ws);
  if(base > ws_size) return;
  // merged-hopfield hidden buffer (77.4 MB) if it fits, else 2-chunk overlay on Qb/Kb
  u16* hidden; int hop_merged;
  if(base + (size_t)M*3072*2 <= ws_size){ hidden = (u16*)(d_ws) + base/2; hop_merged = 1; }
  else { hidden = Qb; hop_merged = 0; }

  // ---- weights live inside d_out (28.3 MB of 38.5 MB; fully dead before decode write) ----
  u16* Wall = (u16*)d_out;
  u16* Wqkb = Wall;               // 2 x [Wq(768 rows); Wk(768 rows)] x 768
  u16* WqkT = Wall + 2359296;     // 2 x 768 x [WqT | WkT] (stride 1536)
  u16* WhnT = Wall + 4718592;     // 2 x 3072 x 768
  u16* WhnB = Wall + 9437184;     // 2 x 768 x 3072 (row-major, ldb 3072)
  u16* xb    = Qb;                // encode-time overlay
  u16* WencT = Kb;                // encode-time overlay
  u16* WdecT = Kb;                // decode-time overlay

  // ---- weight prep ----
  for(int b=0;b<2;b++){
    cvt_k<<<512,256,0,stream>>>(Wq + (size_t)b*589824, Wqkb + (size_t)b*1179648, 589824);
    cvt_k<<<512,256,0,stream>>>(Wk + (size_t)b*589824, Wqkb + (size_t)b*1179648 + 589824, 589824);
    tr_k<<<dim3(24,24),256,0,stream>>>(Wq + (size_t)b*589824, WqkT + (size_t)b*1179648, 768,768, 1536, 0);
    tr_k<<<dim3(24,24),256,0,stream>>>(Wk + (size_t)b*589824, WqkT + (size_t)b*1179648, 768,768, 1536, 768);
    tr_k<<<dim3(96,24),256,0,stream>>>(Whn + (size_t)b*2359296, WhnT + (size_t)b*2359296, 768,3072, 768, 0);
    cvt_k<<<2048,256,0,stream>>>(Whn + (size_t)b*2359296, WhnB + (size_t)b*2359296, 2359296);
  }

  // ---- encode: t = [cls; x@W_enc + b_enc] + pos ----
  cvt_k<<<1024,256,0,stream>>>(x, xb, MX*768);
  tr_k<<<dim3(24,24),256,0,stream>>>(W_enc, WencT, 768,768, 768, 0);
  fill_cls_k<<<64,256,0,stream>>>(t, cls, pos);
  gemm_bt<3,0><<<dim3(6,98),256,0,stream>>>(xb, nullptr, WencT, nullptr, nullptr, t,
                                            MX, 768, 768, 768, 768, nullptr, nullptr,
                                            b_enc, pos, nullptr, 0);

  // ---- energy-descent blocks ----
  for(int blk=0; blk<2; blk++){
    for(int s=0; s<4; s++){
      norm_k<<<M,256,0,stream>>>(t, g, gamma, bias, blk, 0);
      if(hop_merged){
        gemm_bt<1,0><<<dim3(24,99),256,0,stream>>>(g, nullptr,
            WhnT + (size_t)blk*2359296,
            hidden, nullptr, nullptr, M, 3072, 768, 768, 3072, nullptr, nullptr,
            nullptr, nullptr, nullptr, 0);
        gemm_bt<2,0><<<dim3(6,99),256,0,stream>>>(hidden, nullptr,
            WhnB + (size_t)blk*2359296,
            nullptr, nullptr, t, M, 768, 3072, 3072, 768, nullptr, nullptr,
            nullptr, nullptr, araw, blk);
      } else {
        for(int c=0;c<2;c++){
          gemm_bt<1,0><<<dim3(12,99),256,0,stream>>>(g, nullptr,
              WhnT + (size_t)blk*2359296 + (size_t)c*1536*768,
              hidden, nullptr, nullptr, M, 1536, 768, 768, 1536, nullptr, nullptr,
              nullptr, nullptr, nullptr, 0);
          gemm_bt<2,0><<<dim3(6,99),256,0,stream>>>(hidden, nullptr,
              WhnB + (size_t)blk*2359296 + (size_t)c*1536,
              nullptr, nullptr, t, M, 768, 1536, 3072, 768, nullptr, nullptr,
              nullptr, nullptr, araw, blk);
        }
      }
      // Q,K projection (dual store row-major + transposed QT/KT)
      gemm_bt<5,0><<<dim3(12,99),256,0,stream>>>(g, nullptr, Wqkb + (size_t)blk*1179648,
            Qb, Kb, nullptr, M, 1536, 768, 768, 768, QTb, KTb,
            nullptr, nullptr, nullptr, 0);
      // fused attention: Qb := Gq, Kb := Gk (in place)
      attn_k<<<768,256,0,stream>>>(Qb, Kb, QTb, KTb);
      // gradient projection (merged K=1536, split-A)
      gemm_bt<2,1><<<dim3(6,99),256,0,stream>>>(Qb, Kb, WqkT + (size_t)blk*1179648,
            nullptr, nullptr, t, M, 768, 1536, 1536, 768, nullptr, nullptr,
            nullptr, nullptr, araw, blk);
    }
  }

  // ---- decode: LN -> GEMM -> drop CLS ----
  tr_k<<<dim3(24,24),256,0,stream>>>(W_dec, WdecT, 768,768, 768, 0);
  norm_k<<<M,256,0,stream>>>(t, g, ln_g, ln_b, 0, 1);
  gemm_bt<4,0><<<dim3(6,99),256,0,stream>>>(g, nullptr, WdecT, nullptr, nullptr, out,
                                            M, 768, 768, 768, 768, nullptr, nullptr,
                                            b_dec, nullptr, nullptr, 0);
}